// Round 5
// baseline (179.622 us; speedup 1.0000x reference)
//
#include <hip/hip_runtime.h>
#include <math.h>

#define BB 64
#define LL 1024
#define HH 256
#define TT 128
#define D_ID 128
#define D_SZ 64
#define D_POS 128
#define DX 192   // D_ID + D_SZ

typedef short s16x8 __attribute__((ext_vector_type(8)));
typedef float f32x16 __attribute__((ext_vector_type(16)));
typedef unsigned short u16x8 __attribute__((ext_vector_type(8)));

__device__ __forceinline__ unsigned short f2bf(float f) {
    unsigned u = __float_as_uint(f);
    unsigned r = u + 0x7fffu + ((u >> 16) & 1u);   // RNE
    return (unsigned short)(r >> 16);
}

__device__ __forceinline__ s16x8 pack8(float4 a, float4 b) {
    u16x8 p;
    p[0] = f2bf(a.x); p[1] = f2bf(a.y); p[2] = f2bf(a.z); p[3] = f2bf(a.w);
    p[4] = f2bf(b.x); p[5] = f2bf(b.y); p[6] = f2bf(b.z); p[7] = f2bf(b.w);
    return (s16x8)p;
}

// =====================================================================
// N1: gates(direct-embed) + proj tiles t0 in {0,32,64} + svrv(t<127).
//   All parts are h_new-independent. Gates blocks [0,256) land 1/CU;
//   proj/svrv blocks backfill the idle SIMDs -> N1 ~ max, not sum.
//   gates reads embeddings DIRECTLY (no xh_t): per-k working set is
//   ~8 KB (one 128B line per row) -> L1-resident; summation order is
//   bitwise-identical to the xh_t version.
// =====================================================================
__global__ void fused1_kernel(const int* __restrict__ obj_id,
                              const int* __restrict__ obj_size,
                              const float* __restrict__ h0,
                              const float* __restrict__ c0,
                              const float* __restrict__ obj_id_table,
                              const float* __restrict__ obj_size_table,
                              const float* __restrict__ history,
                              const float* __restrict__ pos_table,
                              const float* __restrict__ W_ih,
                              const float* __restrict__ W_hh,
                              const float* __restrict__ b_ih,
                              const float* __restrict__ b_hh,
                              const float* __restrict__ attn_W,
                              const float* __restrict__ scorer_W,
                              const float* __restrict__ reuse_W,
                              float* __restrict__ h_new,
                              unsigned short* __restrict__ hp,
                              float* __restrict__ sv,
                              float* __restrict__ rv) {
    int blk = blockIdx.x;
    int tid = threadIdx.x;

    if (blk < 256) {
        // ---- gates, j = blk; wave q owns W row q*HH+j (scalar loads)
        int j = blk;
        int b = tid & 63;
        int q = __builtin_amdgcn_readfirstlane(tid >> 6);
        int r = q * HH + j;
        __shared__ float gS[256];

        const float* idrow = obj_id_table + (size_t)obj_id[b] * D_ID;
        const float* szrow = obj_size_table + (size_t)obj_size[b] * D_SZ;
        const float* h0row = h0 + (size_t)b * HH;
        const float* wi = W_ih + (size_t)r * DX;
        const float* wh = W_hh + (size_t)r * HH;

        float acc = b_ih[r] + b_hh[r];
#pragma unroll 16
        for (int k = 0; k < D_ID; ++k)
            acc += wi[k] * idrow[k];
#pragma unroll 16
        for (int k = 0; k < D_SZ; ++k)
            acc += wi[D_ID + k] * szrow[k];
#pragma unroll 16
        for (int k = 0; k < HH; ++k)
            acc += wh[k] * h0row[k];
        gS[q * 64 + b] = acc;
        __syncthreads();

        if (tid < 64) {
            float ig = 1.f / (1.f + expf(-gS[tid]));
            float fg = 1.f / (1.f + expf(-gS[64 + tid]));
            float gg = tanhf(gS[128 + tid]);
            float og = 1.f / (1.f + expf(-gS[192 + tid]));
            float c = fg * c0[tid * HH + j] + ig * gg;
            h_new[tid * HH + j] = og * tanhf(c);
        }
        return;
    }

    if (blk < 448) {
        // ---- proj tiles t0 in {0,32,64}: block p = (b, ti), 4 waves = 4 d0.
        // b on XCD b&7 (matches attn's decode); history rows shared by the
        // block's 4 waves -> L1 hits.
        int p = blk - 256;               // [0,192)
        int x = p & 7, g = p >> 3;       // g in [0,24)
        int gb = g / 3;
        int b = x + 8 * gb;
        int ti = g - 3 * gb;
        int w = tid >> 6;
        int t0 = ti * 32, d0 = w * 32;
        int lane = tid & 63;
        int ln = lane & 31, half = lane >> 5;

        int t = t0 + ln;                 // <= 95, never h_new
        const float* arow = history + ((size_t)b * (TT - 1) + t) * HH;
        const float* brow = attn_W + (size_t)(d0 + ln) * HH;

        f32x16 acc;
#pragma unroll
        for (int r = 0; r < 16; ++r) acc[r] = 0.f;

#pragma unroll
        for (int ks = 0; ks < 16; ++ks) {
            int off = ks * 16 + half * 8;
            float4 a0 = *(const float4*)(arow + off);
            float4 a1 = *(const float4*)(arow + off + 4);
            float4 b0 = *(const float4*)(brow + off);
            float4 b1 = *(const float4*)(brow + off + 4);
            acc = __builtin_amdgcn_mfma_f32_32x32x16_bf16(
                pack8(a0, a1), pack8(b0, b1), acc, 0, 0, 0);
        }
#pragma unroll
        for (int r = 0; r < 16; ++r) {
            int tt = t0 + (r & 3) + 8 * (r >> 2) + 4 * half;
            hp[((size_t)b * TT + tt) * D_ID + d0 + ln] = f2bf(acc[r]);
        }
        return;
    }

    // ---- svrv for t < 127 (t=127 needs h_new -> N2)
    {
        int b = blk - 448;               // [0,64)
        int which = tid >> 7;
        int t = tid & 127;
        if (t == TT - 1) return;
        const float* w = which ? reuse_W : scorer_W;
        const float* hrow = history + ((size_t)b * (TT - 1) + t) * HH;
        float acc = 0.f;
#pragma unroll 8
        for (int k = 0; k < HH / 4; ++k) {
            float4 hv = *(const float4*)(hrow + 4 * k);
            float4 wv = *(const float4*)(w + 4 * k);
            acc += hv.x * wv.x + hv.y * wv.y + hv.z * wv.z + hv.w * wv.w;
        }
        const float* prow = pos_table + (size_t)t * D_POS;
#pragma unroll 8
        for (int k = 0; k < D_POS / 4; ++k) {
            float4 pv = *(const float4*)(prow + 4 * k);
            float4 wv = *(const float4*)(w + HH + 4 * k);
            acc += pv.x * wv.x + pv.y * wv.y + pv.z * wv.z + pv.w * wv.w;
        }
        (which ? rv : sv)[b * TT + t] = acc;
    }
}

// =====================================================================
// N2: the h_new-dependent remainder: proj t0=96 tiles + svrv[127].
//   Blocks [0,64): b = blk, 4 waves = 4 d0 tiles at t0=96.
//   Block 64: svrv t=127 (128 threads, one full 384-dot each,
//   float4 association identical to the svrv loop above).
// =====================================================================
__global__ void fused2_kernel(const float* __restrict__ history,
                              const float* __restrict__ h_new,
                              const float* __restrict__ attn_W,
                              const float* __restrict__ pos_table,
                              const float* __restrict__ scorer_W,
                              const float* __restrict__ reuse_W,
                              unsigned short* __restrict__ hp,
                              float* __restrict__ sv,
                              float* __restrict__ rv) {
    int blk = blockIdx.x;
    int tid = threadIdx.x;

    if (blk < 64) {
        int b = blk;
        int w = tid >> 6;
        int t0 = 96, d0 = w * 32;
        int lane = tid & 63;
        int ln = lane & 31, half = lane >> 5;

        int t = t0 + ln;
        const float* arow = (t < TT - 1)
            ? history + ((size_t)b * (TT - 1) + t) * HH
            : h_new + (size_t)b * HH;
        const float* brow = attn_W + (size_t)(d0 + ln) * HH;

        f32x16 acc;
#pragma unroll
        for (int r = 0; r < 16; ++r) acc[r] = 0.f;

#pragma unroll
        for (int ks = 0; ks < 16; ++ks) {
            int off = ks * 16 + half * 8;
            float4 a0 = *(const float4*)(arow + off);
            float4 a1 = *(const float4*)(arow + off + 4);
            float4 b0 = *(const float4*)(brow + off);
            float4 b1 = *(const float4*)(brow + off + 4);
            acc = __builtin_amdgcn_mfma_f32_32x32x16_bf16(
                pack8(a0, a1), pack8(b0, b1), acc, 0, 0, 0);
        }
#pragma unroll
        for (int r = 0; r < 16; ++r) {
            int tt = t0 + (r & 3) + 8 * (r >> 2) + 4 * half;
            hp[((size_t)b * TT + tt) * D_ID + d0 + ln] = f2bf(acc[r]);
        }
        return;
    }

    // ---- svrv at t = 127
    if (tid < 128) {
        int b = tid & 63;
        int which = tid >> 6;
        const float* w = which ? reuse_W : scorer_W;
        const float* hrow = h_new + (size_t)b * HH;
        float acc = 0.f;
#pragma unroll 8
        for (int k = 0; k < HH / 4; ++k) {
            float4 hv = *(const float4*)(hrow + 4 * k);
            float4 wv = *(const float4*)(w + 4 * k);
            acc += hv.x * wv.x + hv.y * wv.y + hv.z * wv.z + hv.w * wv.w;
        }
        const float* prow = pos_table + (size_t)(TT - 1) * D_POS;
#pragma unroll 8
        for (int k = 0; k < D_POS / 4; ++k) {
            float4 pv = *(const float4*)(prow + 4 * k);
            float4 wv = *(const float4*)(w + HH + 4 * k);
            acc += pv.x * wv.x + pv.y * wv.y + pv.z * wv.z + pv.w * wv.w;
        }
        (which ? rv : sv)[b * TT + TT - 1] = acc;
    }
}

// =====================================================================
// N3 attn, K-SPLIT: 2048 blocks x 128 thr (2 waves). Wave wv handles
// d-half wv*64..wv*64+63 (4 of 8 K-steps): half the gather + half the
// hp fragment loads per wave, 2x waves/CU (16) vs R4's 8. Partials
// combined through 16 KB LDS; wave 1 does softmax + heads (identical
// code to R4; only new rounding is one fp32 add reassociation).
// =====================================================================
__global__ void __launch_bounds__(128)
attn_kernel(const int* __restrict__ cache_lines,
            const float* __restrict__ obj_id_table,
            const unsigned short* __restrict__ hp,
            const float* __restrict__ sv,
            const float* __restrict__ rv,
            const float* __restrict__ scorer_b,
            const float* __restrict__ reuse_b,
            float* __restrict__ logits,
            float* __restrict__ out_reuse) {
    int i  = blockIdx.x;
    int b  = (i & 7) + 8 * ((i >> 3) & 7);
    int l0 = (i >> 6) * 32;
    int tid = threadIdx.x;
    int wv = tid >> 6;
    int lane = tid & 63;
    int ln = lane & 31, half = lane >> 5;

    __shared__ float accS[4][4][64][4];   // 16 KB partial C

    // ---- Q gather -> registers (this wave's 4 K-steps only)
    int cl = cache_lines[b * LL + l0 + ln];
    const float* qrow = obj_id_table + (size_t)cl * D_ID + half * 8;
    float4 qa[4], qb[4];
#pragma unroll
    for (int ks = 0; ks < 4; ++ks) {
        qa[ks] = *(const float4*)(qrow + (wv * 4 + ks) * 16);
        qb[ks] = *(const float4*)(qrow + (wv * 4 + ks) * 16 + 4);
    }

    // ---- sv/rv + biases (overlap the gather)
    float sv_r[4], rv_r[4];
#pragma unroll
    for (int tt = 0; tt < 4; ++tt) {
        sv_r[tt] = sv[b * TT + tt * 32 + ln];
        rv_r[tt] = rv[b * TT + tt * 32 + ln];
    }
    float sb = scorer_b[0], rb = reuse_b[0];

    s16x8 qf[4];
#pragma unroll
    for (int ks = 0; ks < 4; ++ks) qf[ks] = pack8(qa[ks], qb[ks]);

    // ---- partial scores over this wave's d-half
    const unsigned short* hpb = hp + (size_t)b * TT * D_ID + half * 8;
    f32x16 acc[4];
#pragma unroll
    for (int tt = 0; tt < 4; ++tt)
#pragma unroll
        for (int r = 0; r < 16; ++r) acc[tt][r] = 0.f;

#pragma unroll
    for (int k = 0; k < 4; ++k) {
#pragma unroll
        for (int tt = 0; tt < 4; ++tt) {
            s16x8 bf = *(const s16x8*)(hpb + (size_t)(tt * 32 + ln) * D_ID +
                                       (wv * 4 + k) * 16);
            acc[tt] = __builtin_amdgcn_mfma_f32_32x32x16_bf16(qf[k], bf, acc[tt], 0, 0, 0);
        }
    }

    if (wv == 0) {
#pragma unroll
        for (int tt = 0; tt < 4; ++tt)
#pragma unroll
            for (int rq = 0; rq < 4; ++rq) {
                float4 v = make_float4(acc[tt][4 * rq + 0], acc[tt][4 * rq + 1],
                                       acc[tt][4 * rq + 2], acc[tt][4 * rq + 3]);
                *(float4*)&accS[tt][rq][lane][0] = v;
            }
    }
    __syncthreads();
    if (wv == 0) return;

    // ---- combine (low-k partial first) + softmax + heads (R4 code)
#pragma unroll
    for (int tt = 0; tt < 4; ++tt)
#pragma unroll
        for (int rq = 0; rq < 4; ++rq) {
            float4 p = *(const float4*)&accS[tt][rq][lane][0];
            acc[tt][4 * rq + 0] = p.x + acc[tt][4 * rq + 0];
            acc[tt][4 * rq + 1] = p.y + acc[tt][4 * rq + 1];
            acc[tt][4 * rq + 2] = p.z + acc[tt][4 * rq + 2];
            acc[tt][4 * rq + 3] = p.w + acc[tt][4 * rq + 3];
        }

#pragma unroll
    for (int r = 0; r < 16; ++r) {
        float v0 = acc[0][r], v1 = acc[1][r], v2 = acc[2][r], v3 = acc[3][r];
        float m = fmaxf(fmaxf(v0, v1), fmaxf(v2, v3));
#pragma unroll
        for (int off = 1; off < 32; off <<= 1) m = fmaxf(m, __shfl_xor(m, off));
        float e0 = __expf(v0 - m), e1 = __expf(v1 - m),
              e2 = __expf(v2 - m), e3 = __expf(v3 - m);
        float s  = e0 + e1 + e2 + e3;
        float lg = e0 * sv_r[0] + e1 * sv_r[1] + e2 * sv_r[2] + e3 * sv_r[3];
        float rg = e0 * rv_r[0] + e1 * rv_r[1] + e2 * rv_r[2] + e3 * rv_r[3];
#pragma unroll
        for (int off = 1; off < 32; off <<= 1) {
            s  += __shfl_xor(s, off);
            lg += __shfl_xor(lg, off);
            rg += __shfl_xor(rg, off);
        }
        if (ln == 0) {
            int row = (r & 3) + 8 * (r >> 2) + 4 * half;
            int l = l0 + row;
            logits[b * LL + l] = lg / s + sb;
            out_reuse[b * LL + l] = rg / s + rb;
        }
    }
}

// -------------------------------------- masked softmax over L per batch
__global__ void finalsm_kernel(const float* __restrict__ logits,
                               const int* __restrict__ lengths,
                               float* __restrict__ out_probs) {
    int b = blockIdx.x;
    int tid = threadIdx.x;
    int valid = max(lengths[b], 1);
    float v[4];
    float m = -1e30f;
#pragma unroll
    for (int i = 0; i < 4; ++i) {
        int l = tid + 256 * i;
        v[i] = (l < valid) ? logits[b * LL + l] : -1e30f;
        m = fmaxf(m, v[i]);
    }
#pragma unroll
    for (int off = 1; off < 64; off <<= 1) m = fmaxf(m, __shfl_xor(m, off));
    __shared__ float redm[4];
    __shared__ float reds[4];
    int wave = tid >> 6;
    if ((tid & 63) == 0) redm[wave] = m;
    __syncthreads();
    m = fmaxf(fmaxf(redm[0], redm[1]), fmaxf(redm[2], redm[3]));
    float e[4];
    float s = 0.f;
#pragma unroll
    for (int i = 0; i < 4; ++i) {
        int l = tid + 256 * i;
        e[i] = (l < valid) ? expf(v[i] - m) : 0.f;
        s += e[i];
    }
#pragma unroll
    for (int off = 1; off < 64; off <<= 1) s += __shfl_xor(s, off);
    if ((tid & 63) == 0) reds[wave] = s;
    __syncthreads();
    s = reds[0] + reds[1] + reds[2] + reds[3];
    float inv = 1.f / s;
#pragma unroll
    for (int i = 0; i < 4; ++i)
        out_probs[b * LL + tid + 256 * i] = e[i] * inv;
}

extern "C" void kernel_launch(void* const* d_in, const int* in_sizes, int n_in,
                              void* d_out, int out_size, void* d_ws, size_t ws_size,
                              hipStream_t stream) {
    const int*   obj_id         = (const int*)d_in[0];
    const int*   obj_size       = (const int*)d_in[1];
    const int*   cache_lines    = (const int*)d_in[2];
    const int*   lengths        = (const int*)d_in[3];
    const float* c0             = (const float*)d_in[4];
    const float* h0             = (const float*)d_in[5];
    const float* history        = (const float*)d_in[6];
    const float* obj_id_table   = (const float*)d_in[7];
    const float* obj_size_table = (const float*)d_in[8];
    const float* pos_table      = (const float*)d_in[9];
    const float* W_ih           = (const float*)d_in[10];
    const float* W_hh           = (const float*)d_in[11];
    const float* b_ih           = (const float*)d_in[12];
    const float* b_hh           = (const float*)d_in[13];
    const float* attn_W         = (const float*)d_in[14];
    const float* scorer_W       = (const float*)d_in[15];
    const float* scorer_b       = (const float*)d_in[16];
    const float* reuse_W        = (const float*)d_in[17];
    const float* reuse_b        = (const float*)d_in[18];

    float* out = (float*)d_out;
    float* out_probs = out;                 // (B, L)
    float* out_reuse = out + BB * LL;       // (B, L)

    char* ws = (char*)d_ws;
    float*          h_new  = (float*)(ws);                    // 64 KB
    unsigned short* hp     = (unsigned short*)(ws + 65536);   // 2 MB bf16
    float*          sv     = (float*)(ws + 65536 + 2097152);
    float*          rv     = (float*)(ws + 65536 + 2097152 + 32768);
    float*          logits = (float*)(ws + 65536 + 2097152 + 65536);  // 256 KB

    // N1: gates + 3/4 of proj + svrv(t<127)  (all h_new-independent)
    hipLaunchKernelGGL(fused1_kernel, dim3(512), dim3(256), 0, stream,
                       obj_id, obj_size, h0, c0, obj_id_table, obj_size_table,
                       history, pos_table, W_ih, W_hh, b_ih, b_hh,
                       attn_W, scorer_W, reuse_W, h_new, hp, sv, rv);
    // N2: h_new-dependent remainder: proj t0=96 + svrv[127]
    hipLaunchKernelGGL(fused2_kernel, dim3(65), dim3(256), 0, stream,
                       history, h_new, attn_W, pos_table, scorer_W, reuse_W,
                       hp, sv, rv);
    // N3: attn (K-split, 2 waves/tile, 16 waves/CU)
    hipLaunchKernelGGL(attn_kernel, dim3(BB * 32), dim3(128), 0, stream,
                       cache_lines, obj_id_table, hp, sv, rv,
                       scorer_b, reuse_b, logits, out_reuse);
    // N4: masked softmax
    hipLaunchKernelGGL(finalsm_kernel, dim3(BB), dim3(256), 0, stream,
                       logits, lengths, out_probs);
}

// Round 6
// 166.964 us; speedup vs baseline: 1.0758x; 1.0758x over previous
//
#include <hip/hip_runtime.h>
#include <math.h>

#define BB 64
#define LL 1024
#define HH 256
#define TT 128
#define D_ID 128
#define D_SZ 64
#define D_POS 128
#define DX 192   // D_ID + D_SZ

typedef short s16x8 __attribute__((ext_vector_type(8)));
typedef float f32x16 __attribute__((ext_vector_type(16)));
typedef unsigned short u16x8 __attribute__((ext_vector_type(8)));

__device__ __forceinline__ unsigned short f2bf(float f) {
    unsigned u = __float_as_uint(f);
    unsigned r = u + 0x7fffu + ((u >> 16) & 1u);   // RNE
    return (unsigned short)(r >> 16);
}

__device__ __forceinline__ s16x8 pack8(float4 a, float4 b) {
    u16x8 p;
    p[0] = f2bf(a.x); p[1] = f2bf(a.y); p[2] = f2bf(a.z); p[3] = f2bf(a.w);
    p[4] = f2bf(b.x); p[5] = f2bf(b.y); p[6] = f2bf(b.z); p[7] = f2bf(b.w);
    return (s16x8)p;
}

// ============================== N1: embed + COALESCED qT convert
//   [0,112):     xh_t[448][64] = concat(x, h0)^T  (R0 embed, unchanged)
//   [112,4208):  obj_id_table fp32 -> qT bf16. Each thread converts 8
//     LANE-CONTIGUOUS floats (32 B/lane stride across the wave) -> pure
//     streaming, ~48 MB total. qT bytes == pack8(f2bf) of the old path,
//     and qT is L2/L3-warm when attn runs (the fp32 table is L3-cold
//     every iteration: the 2x268MB harness fills flush L3).
__global__ void embed_kernel(const int* __restrict__ obj_id,
                             const int* __restrict__ obj_size,
                             const float* __restrict__ h0,
                             const float* __restrict__ obj_id_table,
                             const float* __restrict__ obj_size_table,
                             float* __restrict__ xh_t,
                             unsigned short* __restrict__ qT) {
    int blk = blockIdx.x;
    int tid = threadIdx.x;

    if (blk < 112) {
        int b = tid & 63;
        int k = blk * 4 + (tid >> 6);
        float v;
        if (k < D_ID)      v = obj_id_table[(size_t)obj_id[b] * D_ID + k];
        else if (k < DX)   v = obj_size_table[(size_t)obj_size[b] * D_SZ + (k - D_ID)];
        else               v = h0[b * HH + (k - DX)];
        xh_t[k * 64 + b] = v;
        return;
    }

    // ---- table convert: 1,048,576 threads x 8 floats = 8M elems
    size_t g = ((size_t)(blk - 112) * 256 + tid) * 8;
    float4 a = *(const float4*)(obj_id_table + g);
    float4 b = *(const float4*)(obj_id_table + g + 4);
    *(s16x8*)(qT + g) = pack8(a, b);
}

// --------------- gates + fused LSTM activation (R0, unchanged)
__global__ void gates_kernel(const float* __restrict__ xh_t,
                             const float* __restrict__ W_ih,
                             const float* __restrict__ W_hh,
                             const float* __restrict__ b_ih,
                             const float* __restrict__ b_hh,
                             const float* __restrict__ c0,
                             float* __restrict__ h_new) {
    int j = blockIdx.x;
    int tid = threadIdx.x;
    int b = tid & 63;
    int q = __builtin_amdgcn_readfirstlane(tid >> 6);
    int r = q * HH + j;
    __shared__ float gS[256];

    float acc = b_ih[r] + b_hh[r];
    const float* wi = W_ih + (size_t)r * DX;
    const float* wh = W_hh + (size_t)r * HH;
#pragma unroll 16
    for (int k = 0; k < DX; ++k)
        acc += wi[k] * xh_t[k * 64 + b];
#pragma unroll 16
    for (int k = 0; k < HH; ++k)
        acc += wh[k] * xh_t[(DX + k) * 64 + b];
    gS[q * 64 + b] = acc;
    __syncthreads();

    if (tid < 64) {
        float ig = 1.f / (1.f + expf(-gS[tid]));
        float fg = 1.f / (1.f + expf(-gS[64 + tid]));
        float gg = tanhf(gS[128 + tid]);
        float og = 1.f / (1.f + expf(-gS[192 + tid]));
        float c = fg * c0[tid * HH + j] + ig * gg;
        h_new[tid * HH + j] = og * tanhf(c);
    }
}

// ------------- fused: HP(bf16) = hist @ attn_W^T (MFMA)  +  sv/rv dots
// (R0, unchanged)
__global__ void proj_kernel(const float* __restrict__ history,
                            const float* __restrict__ h_new,
                            const float* __restrict__ attn_W,
                            const float* __restrict__ pos_table,
                            const float* __restrict__ scorer_W,
                            const float* __restrict__ reuse_W,
                            unsigned short* __restrict__ hp,
                            float* __restrict__ sv,
                            float* __restrict__ rv) {
    int blk = blockIdx.x;
    int tid = threadIdx.x;

    if (blk >= BB * 16) {
        // ---- svrv part: idx = b*4 + which*2 + thalf
        int idx = blk - BB * 16;
        int b = idx >> 2;
        int which = (idx >> 1) & 1;
        int t = (idx & 1) * 64 + tid;
        const float* w = which ? reuse_W : scorer_W;
        const float* hrow = (t < TT - 1)
            ? history + ((size_t)b * (TT - 1) + t) * HH
            : h_new + (size_t)b * HH;
        float acc = 0.f;
#pragma unroll 8
        for (int k = 0; k < HH / 4; ++k) {
            float4 hv = *(const float4*)(hrow + 4 * k);
            float4 wv = *(const float4*)(w + 4 * k);
            acc += hv.x * wv.x + hv.y * wv.y + hv.z * wv.z + hv.w * wv.w;
        }
        const float* prow = pos_table + (size_t)t * D_POS;
#pragma unroll 8
        for (int k = 0; k < D_POS / 4; ++k) {
            float4 pv = *(const float4*)(prow + 4 * k);
            float4 wv = *(const float4*)(w + HH + 4 * k);
            acc += pv.x * wv.x + pv.y * wv.y + pv.z * wv.z + pv.w * wv.w;
        }
        (which ? rv : sv)[b * TT + t] = acc;
        return;
    }

    // ---- proj part: one wave, direct-from-global MFMA fragments
    int b  = blk >> 4;
    int t0 = ((blk >> 2) & 3) * 32;
    int d0 = (blk & 3) * 32;
    int lane = tid;
    int ln = lane & 31, half = lane >> 5;

    int t = t0 + ln;
    const float* arow = (t < TT - 1)
        ? history + ((size_t)b * (TT - 1) + t) * HH
        : h_new + (size_t)b * HH;
    const float* brow = attn_W + (size_t)(d0 + ln) * HH;

    f32x16 acc;
#pragma unroll
    for (int r = 0; r < 16; ++r) acc[r] = 0.f;

#pragma unroll
    for (int ks = 0; ks < 16; ++ks) {
        int off = ks * 16 + half * 8;
        float4 a0 = *(const float4*)(arow + off);
        float4 a1 = *(const float4*)(arow + off + 4);
        float4 b0 = *(const float4*)(brow + off);
        float4 b1 = *(const float4*)(brow + off + 4);
        acc = __builtin_amdgcn_mfma_f32_32x32x16_bf16(
            pack8(a0, a1), pack8(b0, b1), acc, 0, 0, 0);
    }

#pragma unroll
    for (int r = 0; r < 16; ++r) {
        int tt = t0 + (r & 3) + 8 * (r >> 2) + 4 * half;
        hp[((size_t)b * TT + tt) * D_ID + d0 + ln] = f2bf(acc[r]);
    }
}

// ---- scores = Q@HP^T via mfma_32x32x16_bf16, softmax over t, heads.
// R3 barrier-free single-wave form, but Q gathered as 16B bf16 fragments
// DIRECTLY from qT (bytes bit-identical to the pack8 path): half the
// gather bytes/instructions, zero pack VALU, and the source is L2/L3-warm.
__global__ void __launch_bounds__(64, 2)
attn_kernel(const int* __restrict__ cache_lines,
            const unsigned short* __restrict__ qT,
            const unsigned short* __restrict__ hp,
            const float* __restrict__ sv,
            const float* __restrict__ rv,
            const float* __restrict__ scorer_b,
            const float* __restrict__ reuse_b,
            float* __restrict__ logits,
            float* __restrict__ out_reuse) {
    int b  = blockIdx.x >> 5;
    int l0 = (blockIdx.x & 31) * 32;
    int lane = threadIdx.x;
    int ln = lane & 31, half = lane >> 5;

    // ---- Q gather -> registers (issued first)
    int cl = cache_lines[b * LL + l0 + ln];
    const unsigned short* qrow = qT + (size_t)cl * D_ID + half * 8;
    s16x8 qf[8];
#pragma unroll
    for (int ks = 0; ks < 8; ++ks)
        qf[ks] = *(const s16x8*)(qrow + ks * 16);

    // ---- sv/rv (independent loads, overlap the gather)
    float sv_r[4], rv_r[4];
#pragma unroll
    for (int tt = 0; tt < 4; ++tt) {
        sv_r[tt] = sv[b * TT + tt * 32 + ln];
        rv_r[tt] = rv[b * TT + tt * 32 + ln];
    }
    float sb = scorer_b[0], rb = reuse_b[0];

    // ---- scores = Q @ hp^T; B-fragments direct from global hp
    const unsigned short* hpb = hp + (size_t)b * TT * D_ID + half * 8;
    f32x16 acc[4];
#pragma unroll
    for (int tt = 0; tt < 4; ++tt)
#pragma unroll
        for (int r = 0; r < 16; ++r) acc[tt][r] = 0.f;

#pragma unroll
    for (int k = 0; k < 8; ++k) {
#pragma unroll
        for (int tt = 0; tt < 4; ++tt) {
            s16x8 bf = *(const s16x8*)(hpb + (size_t)(tt * 32 + ln) * D_ID + k * 16);
            acc[tt] = __builtin_amdgcn_mfma_f32_32x32x16_bf16(qf[k], bf, acc[tt], 0, 0, 0);
        }
    }

    // ---- softmax over t (per output row) + heads
#pragma unroll
    for (int r = 0; r < 16; ++r) {
        float v0 = acc[0][r], v1 = acc[1][r], v2 = acc[2][r], v3 = acc[3][r];
        float m = fmaxf(fmaxf(v0, v1), fmaxf(v2, v3));
#pragma unroll
        for (int off = 1; off < 32; off <<= 1) m = fmaxf(m, __shfl_xor(m, off));
        float e0 = __expf(v0 - m), e1 = __expf(v1 - m),
              e2 = __expf(v2 - m), e3 = __expf(v3 - m);
        float s  = e0 + e1 + e2 + e3;
        float lg = e0 * sv_r[0] + e1 * sv_r[1] + e2 * sv_r[2] + e3 * sv_r[3];
        float rg = e0 * rv_r[0] + e1 * rv_r[1] + e2 * rv_r[2] + e3 * rv_r[3];
#pragma unroll
        for (int off = 1; off < 32; off <<= 1) {
            s  += __shfl_xor(s, off);
            lg += __shfl_xor(lg, off);
            rg += __shfl_xor(rg, off);
        }
        if (ln == 0) {
            int row = (r & 3) + 8 * (r >> 2) + 4 * half;
            int l = l0 + row;
            logits[b * LL + l] = lg / s + sb;
            out_reuse[b * LL + l] = rg / s + rb;
        }
    }
}

// -------------------------------------- masked softmax over L per batch
__global__ void finalsm_kernel(const float* __restrict__ logits,
                               const int* __restrict__ lengths,
                               float* __restrict__ out_probs) {
    int b = blockIdx.x;
    int tid = threadIdx.x;
    int valid = max(lengths[b], 1);
    float v[4];
    float m = -1e30f;
#pragma unroll
    for (int i = 0; i < 4; ++i) {
        int l = tid + 256 * i;
        v[i] = (l < valid) ? logits[b * LL + l] : -1e30f;
        m = fmaxf(m, v[i]);
    }
#pragma unroll
    for (int off = 1; off < 64; off <<= 1) m = fmaxf(m, __shfl_xor(m, off));
    __shared__ float redm[4];
    __shared__ float reds[4];
    int wave = tid >> 6;
    if ((tid & 63) == 0) redm[wave] = m;
    __syncthreads();
    m = fmaxf(fmaxf(redm[0], redm[1]), fmaxf(redm[2], redm[3]));
    float e[4];
    float s = 0.f;
#pragma unroll
    for (int i = 0; i < 4; ++i) {
        int l = tid + 256 * i;
        e[i] = (l < valid) ? expf(v[i] - m) : 0.f;
        s += e[i];
    }
#pragma unroll
    for (int off = 1; off < 64; off <<= 1) s += __shfl_xor(s, off);
    if ((tid & 63) == 0) reds[wave] = s;
    __syncthreads();
    s = reds[0] + reds[1] + reds[2] + reds[3];
    float inv = 1.f / s;
#pragma unroll
    for (int i = 0; i < 4; ++i)
        out_probs[b * LL + tid + 256 * i] = e[i] * inv;
}

extern "C" void kernel_launch(void* const* d_in, const int* in_sizes, int n_in,
                              void* d_out, int out_size, void* d_ws, size_t ws_size,
                              hipStream_t stream) {
    const int*   obj_id         = (const int*)d_in[0];
    const int*   obj_size       = (const int*)d_in[1];
    const int*   cache_lines    = (const int*)d_in[2];
    const int*   lengths        = (const int*)d_in[3];
    const float* c0             = (const float*)d_in[4];
    const float* h0             = (const float*)d_in[5];
    const float* history        = (const float*)d_in[6];
    const float* obj_id_table   = (const float*)d_in[7];
    const float* obj_size_table = (const float*)d_in[8];
    const float* pos_table      = (const float*)d_in[9];
    const float* W_ih           = (const float*)d_in[10];
    const float* W_hh           = (const float*)d_in[11];
    const float* b_ih           = (const float*)d_in[12];
    const float* b_hh           = (const float*)d_in[13];
    const float* attn_W         = (const float*)d_in[14];
    const float* scorer_W       = (const float*)d_in[15];
    const float* scorer_b       = (const float*)d_in[16];
    const float* reuse_W        = (const float*)d_in[17];
    const float* reuse_b        = (const float*)d_in[18];

    float* out = (float*)d_out;
    float* out_probs = out;                 // (B, L)
    float* out_reuse = out + BB * LL;       // (B, L)

    char* ws = (char*)d_ws;
    float*          h_new  = (float*)(ws);                     // 64 KB
    unsigned short* hp     = (unsigned short*)(ws + 65536);    // 2 MB bf16
    float*          sv     = (float*)(ws + 2162688);           // 32 KB
    float*          rv     = (float*)(ws + 2195456);           // 32 KB
    float*          xh_t   = (float*)(ws + 2228224);           // 112 KB
    float*          logits = (float*)(ws + 2228224);           // shares xh_t (disjoint lifetime)
    unsigned short* qT     = (unsigned short*)(ws + 4194304);  // 16 MB bf16

    // N1: embed + coalesced fp32->bf16 table convert
    hipLaunchKernelGGL(embed_kernel, dim3(112 + 4096), dim3(256), 0, stream,
                       obj_id, obj_size, h0, obj_id_table, obj_size_table,
                       xh_t, qT);
    // N2: gates (R0)
    hipLaunchKernelGGL(gates_kernel, dim3(HH), dim3(256), 0, stream,
                       xh_t, W_ih, W_hh, b_ih, b_hh, c0, h_new);
    // N3: proj + svrv (R0)
    hipLaunchKernelGGL(proj_kernel, dim3(BB * 16 + BB * 4), dim3(64), 0, stream,
                       history, h_new, attn_W, pos_table, scorer_W, reuse_W,
                       hp, sv, rv);
    // N4: attn (barrier-free, bf16 register gather from L3-warm qT)
    hipLaunchKernelGGL(attn_kernel, dim3(BB * 32), dim3(64), 0, stream,
                       cache_lines, qT, hp, sv, rv,
                       scorer_b, reuse_b, logits, out_reuse);
    // N5: masked softmax
    hipLaunchKernelGGL(finalsm_kernel, dim3(BB), dim3(256), 0, stream,
                       logits, lengths, out_probs);
}